// Round 2
// baseline (1052.208 us; speedup 1.0000x reference)
//
#include <hip/hip_runtime.h>
#include <hip/hip_bf16.h>

typedef _Float16 half8 __attribute__((ext_vector_type(8)));
typedef float f32x4 __attribute__((ext_vector_type(4)));

#define Bsz 32
#define Nseq 2048
#define Edim 1024
#define Hdim 1024
// rows of the big GEMM: M = B*N = 65536, K = E = 1024

// ---------------- kernel 1a: dw[b,h] = dec[b,:] @ w_d[:,h]  (f32) ------------
__global__ void k_dw(const float* __restrict__ dec, const float* __restrict__ w_d,
                     float* __restrict__ dw) {
    int b = blockIdx.x;
    int h = blockIdx.y * 256 + threadIdx.x;
    const float* dr = dec + b * 1024;
    float acc = 0.f;
#pragma unroll 8
    for (int d = 0; d < 1024; ++d)
        acc += dr[d] * w_d[d * 1024 + h];
    dw[b * 1024 + h] = acc;
}

// ------- kernel 1b: split w_e (f32 [E][H]) into fp16 hi/lo, transposed [H][E] -
__global__ void k_split(const float* __restrict__ w_e,
                        _Float16* __restrict__ w_hiT, _Float16* __restrict__ w_loT) {
    __shared__ _Float16 th[32][33];
    __shared__ _Float16 tl[32][33];
    int e0 = blockIdx.x * 32, h0 = blockIdx.y * 32;
    int tx = threadIdx.x & 31, ty = threadIdx.x >> 5;  // ty 0..7
#pragma unroll
    for (int i = 0; i < 4; ++i) {
        int r = ty + i * 8;
        float x = w_e[(size_t)(e0 + r) * 1024 + h0 + tx];
        _Float16 h = (_Float16)x;
        th[r][tx] = h;
        tl[r][tx] = (_Float16)(x - (float)h);
    }
    __syncthreads();
#pragma unroll
    for (int i = 0; i < 4; ++i) {
        int r = ty + i * 8;
        w_hiT[(size_t)(h0 + r) * 1024 + e0 + tx] = th[tx][r];
        w_loT[(size_t)(h0 + r) * 1024 + e0 + tx] = tl[tx][r];
    }
}

// ---------------- kernel 2: scores[m] = sum_h w_out[h]*tanh((enc@w_e)[m,h]+dw[b,h])
// fp16x3 split MFMA (hi*hi + hi*lo + lo*hi), 16x16x32.
// Block: 512 thr (8 waves, 2x4 wave grid). M_TILE=128, H_CHUNK=256, K_STEP=32.
#define SA_PITCH 40   // halves per LDS row (32 data + 8 pad) -> 80B, 2-way bank alias (free)
__global__ __launch_bounds__(512, 2)
void k_scores(const float* __restrict__ enc,
              const _Float16* __restrict__ w_hiT, const _Float16* __restrict__ w_loT,
              const float* __restrict__ dw, const float* __restrict__ w_out,
              float* __restrict__ scores) {
    __shared__ __align__(16) _Float16 sa_hi[128 * SA_PITCH];
    __shared__ __align__(16) _Float16 sa_lo[128 * SA_PITCH];
    __shared__ __align__(16) _Float16 sb_hi[256 * SA_PITCH];
    __shared__ __align__(16) _Float16 sb_lo[256 * SA_PITCH];
    __shared__ float score_lds[128];

    const int tid  = threadIdx.x;
    const int lane = tid & 63;
    const int wave = tid >> 6;
    const int wr = wave >> 2, wc = wave & 3;     // 2 x 4 wave grid
    const int m0 = blockIdx.x * 128;
    const int b  = m0 >> 11;                     // 2048 rows per batch
    const float* dwb = dw + b * 1024;

    const int a_row = tid >> 2, a_seg = (tid & 3) << 3;  // A stage: 8 f32/thread
    const int b_row = tid >> 1, b_seg = (tid & 1) << 4;  // B stage: 16 halves/thread/array

    float sc[4][4];
#pragma unroll
    for (int m = 0; m < 4; ++m)
#pragma unroll
        for (int r = 0; r < 4; ++r) sc[m][r] = 0.f;
    if (tid < 128) score_lds[tid] = 0.f;

    for (int hc = 0; hc < 4; ++hc) {
        const int h0 = hc << 8;
        f32x4 acc[4][4];
#pragma unroll
        for (int m = 0; m < 4; ++m)
#pragma unroll
            for (int n = 0; n < 4; ++n) acc[m][n] = (f32x4){0.f, 0.f, 0.f, 0.f};

        for (int kt = 0; kt < 32; ++kt) {
            const int k0 = kt << 5;
            // ---- stage A (enc f32 -> hi/lo fp16 in LDS) ----
            {
                const float* asrc = enc + (size_t)(m0 + a_row) * 1024 + k0 + a_seg;
                float4 v0 = ((const float4*)asrc)[0];
                float4 v1 = ((const float4*)asrc)[1];
                float vv[8] = {v0.x, v0.y, v0.z, v0.w, v1.x, v1.y, v1.z, v1.w};
                half8 hi, lo;
#pragma unroll
                for (int j = 0; j < 8; ++j) {
                    _Float16 h = (_Float16)vv[j];
                    hi[j] = h;
                    lo[j] = (_Float16)(vv[j] - (float)h);
                }
                *(half8*)&sa_hi[a_row * SA_PITCH + a_seg] = hi;
                *(half8*)&sa_lo[a_row * SA_PITCH + a_seg] = lo;
            }
            // ---- stage B (pre-split fp16, already transposed [H][E]) ----
            {
                const size_t bo = (size_t)(h0 + b_row) * 1024 + k0 + b_seg;
                half8 h0v = ((const half8*)(w_hiT + bo))[0];
                half8 h1v = ((const half8*)(w_hiT + bo))[1];
                half8 l0v = ((const half8*)(w_loT + bo))[0];
                half8 l1v = ((const half8*)(w_loT + bo))[1];
                *(half8*)&sb_hi[b_row * SA_PITCH + b_seg]     = h0v;
                *(half8*)&sb_hi[b_row * SA_PITCH + b_seg + 8] = h1v;
                *(half8*)&sb_lo[b_row * SA_PITCH + b_seg]     = l0v;
                *(half8*)&sb_lo[b_row * SA_PITCH + b_seg + 8] = l1v;
            }
            __syncthreads();

            const int kseg = (lane >> 4) << 3;
            half8 ah[4], al[4], bh[4], bl[4];
#pragma unroll
            for (int m = 0; m < 4; ++m) {
                int off = (wr * 64 + m * 16 + (lane & 15)) * SA_PITCH + kseg;
                ah[m] = *(const half8*)&sa_hi[off];
                al[m] = *(const half8*)&sa_lo[off];
            }
#pragma unroll
            for (int n = 0; n < 4; ++n) {
                int off = (wc * 64 + n * 16 + (lane & 15)) * SA_PITCH + kseg;
                bh[n] = *(const half8*)&sb_hi[off];
                bl[n] = *(const half8*)&sb_lo[off];
            }
#pragma unroll
            for (int m = 0; m < 4; ++m)
#pragma unroll
                for (int n = 0; n < 4; ++n) {
                    acc[m][n] = __builtin_amdgcn_mfma_f32_16x16x32_f16(ah[m], bh[n], acc[m][n], 0, 0, 0);
                    acc[m][n] = __builtin_amdgcn_mfma_f32_16x16x32_f16(ah[m], bl[n], acc[m][n], 0, 0, 0);
                    acc[m][n] = __builtin_amdgcn_mfma_f32_16x16x32_f16(al[m], bh[n], acc[m][n], 0, 0, 0);
                }
            __syncthreads();
        }
        // ---- epilogue: tanh + w_out, accumulate per-lane row partials ----
#pragma unroll
        for (int m = 0; m < 4; ++m)
#pragma unroll
            for (int n = 0; n < 4; ++n) {
                int h = h0 + wc * 64 + n * 16 + (lane & 15);
                float dwv = dwb[h];
                float wo  = w_out[h];
#pragma unroll
                for (int r = 0; r < 4; ++r)
                    sc[m][r] += tanhf(acc[m][n][r] + dwv) * wo;
            }
    }
    // reduce across the 16 col-lanes, then across the 4 wave-cols via LDS atomics
#pragma unroll
    for (int m = 0; m < 4; ++m) {
#pragma unroll
        for (int r = 0; r < 4; ++r) {
            float v = sc[m][r];
            v += __shfl_xor(v, 1);
            v += __shfl_xor(v, 2);
            v += __shfl_xor(v, 4);
            v += __shfl_xor(v, 8);
            sc[m][r] = v;
        }
        if ((lane & 15) == 0) {
            int rb = wr * 64 + m * 16 + (lane >> 4) * 4;
#pragma unroll
            for (int r = 0; r < 4; ++r)
                atomicAdd(&score_lds[rb + r], sc[m][r]);
        }
    }
    __syncthreads();
    if (tid < 128) scores[m0 + tid] = score_lds[tid];
}

// ---------------- kernel 3: masked softmax over N per batch ----------------
// NOTE: mask is a bool input -> harness pushes integer inputs as int32 ("integer -> const int*").
// Reading it as bytes was the Round-1 bug (3/4 of positions looked masked-out).
__global__ void k_softmax(const float* __restrict__ scores,
                          const int* __restrict__ mask,
                          float* __restrict__ probs, float* __restrict__ out_probs) {
    int b = blockIdx.x, tid = threadIdx.x;
    __shared__ float red[8];
    float v[8];
    float m = -INFINITY;
#pragma unroll
    for (int i = 0; i < 8; ++i) {
        int n = tid + i * 256;
        float s = scores[b * 2048 + n];
        s = (mask[b * 2048 + n] != 0) ? s : -INFINITY;
        v[i] = s;
        m = fmaxf(m, s);
    }
    for (int off = 32; off; off >>= 1) m = fmaxf(m, __shfl_xor(m, off));
    if ((tid & 63) == 0) red[tid >> 6] = m;
    __syncthreads();
    m = fmaxf(fmaxf(red[0], red[1]), fmaxf(red[2], red[3]));
    float sum = 0.f;
#pragma unroll
    for (int i = 0; i < 8; ++i) {
        v[i] = expf(v[i] - m);
        sum += v[i];
    }
    for (int off = 32; off; off >>= 1) sum += __shfl_xor(sum, off);
    if ((tid & 63) == 0) red[4 + (tid >> 6)] = sum;
    __syncthreads();
    sum = red[4] + red[5] + red[6] + red[7];
    float inv = 1.0f / sum;
#pragma unroll
    for (int i = 0; i < 8; ++i) {
        int n = tid + i * 256;
        float p = v[i] * inv;
        probs[b * 2048 + n]     = p;
        out_probs[b * 2048 + n] = p;
    }
}

// ---------------- kernel 4: attn[b,e] = sum_n probs[b,n]*enc[b,n,e] ----------
__global__ void k_attn(const float* __restrict__ probs, const float* __restrict__ enc,
                       float* __restrict__ attn) {
    __shared__ float pl[2048];
    int b = blockIdx.x, t = threadIdx.x;
    for (int i = t; i < 2048; i += 256) pl[i] = probs[b * 2048 + i];
    __syncthreads();
    const float* er = enc + (size_t)b * 2048 * 1024;
    float4 acc = {0.f, 0.f, 0.f, 0.f};
    for (int n = 0; n < 2048; ++n) {
        float p = pl[n];
        if (p >= 1e-12f) {  // uniform branch; dropped mass error <= 2e-9
            float4 ev = ((const float4*)(er + (size_t)n * 1024))[t];
            acc.x += p * ev.x;
            acc.y += p * ev.y;
            acc.z += p * ev.z;
            acc.w += p * ev.w;
        }
    }
    ((float4*)(attn + b * 1024))[t] = acc;
}

extern "C" void kernel_launch(void* const* d_in, const int* in_sizes, int n_in,
                              void* d_out, int out_size, void* d_ws, size_t ws_size,
                              hipStream_t stream) {
    const float* enc          = (const float*)d_in[0];  // [32,2048,1024]
    const float* dec          = (const float*)d_in[1];  // [32,1024]
    const int*   mask         = (const int*)d_in[2];    // [32,2048] bool -> int32
    const float* w_e          = (const float*)d_in[3];  // [1024,1024]
    const float* w_d          = (const float*)d_in[4];  // [1024,1024]
    const float* w_out        = (const float*)d_in[5];  // [1024]

    float* out_attn  = (float*)d_out;              // [32*1024]
    float* out_probs = out_attn + Bsz * Hdim;      // [32*2048]

    // workspace layout (~4.7 MB)
    float* dw        = (float*)d_ws;               // 32*1024
    float* scores    = dw + Bsz * Hdim;            // 32*2048
    float* probs     = scores + Bsz * Nseq;        // 32*2048
    _Float16* w_hiT  = (_Float16*)(probs + Bsz * Nseq);  // [1024*1024]
    _Float16* w_loT  = w_hiT + Edim * Hdim;

    k_dw<<<dim3(32, 4), dim3(256), 0, stream>>>(dec, w_d, dw);
    k_split<<<dim3(32, 32), dim3(256), 0, stream>>>(w_e, w_hiT, w_loT);
    k_scores<<<dim3(512), dim3(512), 0, stream>>>(enc, w_hiT, w_loT, dw, w_out, scores);
    k_softmax<<<dim3(32), dim3(256), 0, stream>>>(scores, mask, probs, out_probs);
    k_attn<<<dim3(32), dim3(256), 0, stream>>>(probs, enc, out_attn);
}

// Round 3
// 910.398 us; speedup vs baseline: 1.1558x; 1.1558x over previous
//
#include <hip/hip_runtime.h>
#include <hip/hip_bf16.h>

typedef _Float16 half8 __attribute__((ext_vector_type(8)));
typedef float f32x4 __attribute__((ext_vector_type(4)));

#define Bsz 32
#define Nseq 2048
#define Edim 1024
#define Hdim 1024
// rows of the big GEMM: M = B*N = 65536, K = E = 1024

// ---------------- kernel 1a: dw[b,h] = dec[b,:] @ w_d[:,h]  (f32) ------------
__global__ void k_dw(const float* __restrict__ dec, const float* __restrict__ w_d,
                     float* __restrict__ dw) {
    int b = blockIdx.x;
    int h = blockIdx.y * 256 + threadIdx.x;
    const float* dr = dec + b * 1024;
    float acc = 0.f;
#pragma unroll 8
    for (int d = 0; d < 1024; ++d)
        acc += dr[d] * w_d[d * 1024 + h];
    dw[b * 1024 + h] = acc;
}

// ------- kernel 1b: split w_e (f32 [E][H]) into fp16 hi/lo, transposed [H][E] -
__global__ void k_split(const float* __restrict__ w_e,
                        _Float16* __restrict__ w_hiT, _Float16* __restrict__ w_loT) {
    __shared__ _Float16 th[32][33];
    __shared__ _Float16 tl[32][33];
    int e0 = blockIdx.x * 32, h0 = blockIdx.y * 32;
    int tx = threadIdx.x & 31, ty = threadIdx.x >> 5;  // ty 0..7
#pragma unroll
    for (int i = 0; i < 4; ++i) {
        int r = ty + i * 8;
        float x = w_e[(size_t)(e0 + r) * 1024 + h0 + tx];
        _Float16 h = (_Float16)x;
        th[r][tx] = h;
        tl[r][tx] = (_Float16)(x - (float)h);
    }
    __syncthreads();
#pragma unroll
    for (int i = 0; i < 4; ++i) {
        int r = ty + i * 8;
        w_hiT[(size_t)(h0 + r) * 1024 + e0 + tx] = th[tx][r];
        w_loT[(size_t)(h0 + r) * 1024 + e0 + tx] = tl[tx][r];
    }
}

// ---------------- kernel 2: scores[m] = sum_h w_out[h]*tanh((enc@w_e)[m,h]+dw[b,h])
// fp16x3 split MFMA (hi*hi + hi*lo + lo*hi), 16x16x32.
// Block: 512 thr (8 waves, 2x4 wave grid). M_TILE=128, H_CHUNK=256, K_STEP=32.
//
// LDS layout is kseg-major: tile[kseg][row][8 halves] (16B chunks). Every wave
// access (stage-write and frag-read) is 4 groups of 16 sequential 16B chunks ->
// uniform 8 slots/bank = conflict-free (pitch-40 padding was an 8-lane bank
// cycle: 5.87e7 conflict cycles in round 1).
// Software pipeline: A loads for (kt+1) issue right after the convert of kt
// (WAR-free), B loads right after barrier 2 -> HBM latency hides under MFMA.
__global__ __launch_bounds__(512, 2)
void k_scores(const float* __restrict__ enc,
              const _Float16* __restrict__ w_hiT, const _Float16* __restrict__ w_loT,
              const float* __restrict__ dw, const float* __restrict__ w_out,
              float* __restrict__ scores) {
    __shared__ __align__(16) _Float16 sa_hi[4096];   // [4][128][8]
    __shared__ __align__(16) _Float16 sa_lo[4096];
    __shared__ __align__(16) _Float16 sb_hi[8192];   // [4][256][8]
    __shared__ __align__(16) _Float16 sb_lo[8192];
    __shared__ float score_lds[128];

    const int tid  = threadIdx.x;
    const int lane = tid & 63;
    const int wave = tid >> 6;
    const int wr = wave >> 2, wc = wave & 3;     // 2 x 4 wave grid
    const int m0 = blockIdx.x * 128;
    const int b  = m0 >> 11;                     // 2048 rows per batch
    const float* dwb = dw + b * 1024;

    const int a_row = tid >> 2, a_ks = tid & 3;          // A: 8 f32/thread
    const int b_row = tid >> 1, b_ks2 = (tid & 1) << 1;  // B: 16 halves/thread/array

    float sc[4][4];
#pragma unroll
    for (int m = 0; m < 4; ++m)
#pragma unroll
        for (int r = 0; r < 4; ++r) sc[m][r] = 0.f;
    if (tid < 128) score_lds[tid] = 0.f;

    // prefetch registers
    float4 pa0, pa1;
    half8 pbh0, pbh1, pbl0, pbl1;

    const float* aBase = enc + (size_t)(m0 + a_row) * 1024 + a_ks * 8;

#define LOAD_A(k0) do { \
        const float* _p = aBase + (k0); \
        pa0 = ((const float4*)_p)[0]; \
        pa1 = ((const float4*)_p)[1]; \
    } while (0)
#define LOAD_B(h0, k0) do { \
        const size_t _o = (size_t)((h0) + b_row) * 1024 + (k0) + b_ks2 * 8; \
        pbh0 = ((const half8*)(w_hiT + _o))[0]; \
        pbh1 = ((const half8*)(w_hiT + _o))[1]; \
        pbl0 = ((const half8*)(w_loT + _o))[0]; \
        pbl1 = ((const half8*)(w_loT + _o))[1]; \
    } while (0)

    LOAD_A(0);
    LOAD_B(0, 0);

    for (int hc = 0; hc < 4; ++hc) {
        const int h0 = hc << 8;
        f32x4 acc[4][4];
#pragma unroll
        for (int m = 0; m < 4; ++m)
#pragma unroll
            for (int n = 0; n < 4; ++n) acc[m][n] = (f32x4){0.f, 0.f, 0.f, 0.f};

        for (int kt = 0; kt < 32; ++kt) {
            // ---- convert current A regs to hi/lo fp16 ----
            half8 hiA, loA;
            {
                float q[8] = {pa0.x, pa0.y, pa0.z, pa0.w, pa1.x, pa1.y, pa1.z, pa1.w};
#pragma unroll
                for (int j = 0; j < 8; ++j) {
                    _Float16 h = (_Float16)q[j];
                    hiA[j] = h;
                    loA[j] = (_Float16)(q[j] - (float)h);
                }
            }
            // next step coordinates
            int nkt = kt + 1, nhc = hc;
            if (nkt == 32) { nkt = 0; nhc = hc + 1; }
            const bool more = (nhc < 4);
            // A raw regs are dead after the convert -> prefetch next A now
            if (more) LOAD_A(nkt << 5);

            __syncthreads();   // previous iteration's frag reads complete
            *(half8*)&sa_hi[a_ks * 1024 + a_row * 8] = hiA;
            *(half8*)&sa_lo[a_ks * 1024 + a_row * 8] = loA;
            *(half8*)&sb_hi[(b_ks2    ) * 2048 + b_row * 8] = pbh0;
            *(half8*)&sb_hi[(b_ks2 + 1) * 2048 + b_row * 8] = pbh1;
            *(half8*)&sb_lo[(b_ks2    ) * 2048 + b_row * 8] = pbl0;
            *(half8*)&sb_lo[(b_ks2 + 1) * 2048 + b_row * 8] = pbl1;
            __syncthreads();   // tile ready
            // B regs consumed by the writes above -> prefetch next B now;
            // the loads fly during ds_read + 48 MFMA below.
            if (more) LOAD_B(nhc << 8, nkt << 5);

            const int ks = lane >> 4;
            const int rb = lane & 15;
            half8 ah[4], al[4], bh[4], bl[4];
#pragma unroll
            for (int m = 0; m < 4; ++m) {
                int off = ks * 1024 + (wr * 64 + m * 16 + rb) * 8;
                ah[m] = *(const half8*)&sa_hi[off];
                al[m] = *(const half8*)&sa_lo[off];
            }
#pragma unroll
            for (int n = 0; n < 4; ++n) {
                int off = ks * 2048 + (wc * 64 + n * 16 + rb) * 8;
                bh[n] = *(const half8*)&sb_hi[off];
                bl[n] = *(const half8*)&sb_lo[off];
            }
#pragma unroll
            for (int m = 0; m < 4; ++m)
#pragma unroll
                for (int n = 0; n < 4; ++n) {
                    acc[m][n] = __builtin_amdgcn_mfma_f32_16x16x32_f16(ah[m], bh[n], acc[m][n], 0, 0, 0);
                    acc[m][n] = __builtin_amdgcn_mfma_f32_16x16x32_f16(ah[m], bl[n], acc[m][n], 0, 0, 0);
                    acc[m][n] = __builtin_amdgcn_mfma_f32_16x16x32_f16(al[m], bh[n], acc[m][n], 0, 0, 0);
                }
        }
        // ---- epilogue: tanh + w_out, accumulate per-lane row partials ----
        // branch-free tanh: sign(x) * (1 - 2/(exp(2|x|)+1)); exp->inf gives +-1.
#pragma unroll
        for (int m = 0; m < 4; ++m)
#pragma unroll
            for (int n = 0; n < 4; ++n) {
                int h = h0 + wc * 64 + n * 16 + (lane & 15);
                float dwv = dwb[h];
                float wo  = w_out[h];
#pragma unroll
                for (int r = 0; r < 4; ++r) {
                    float x = acc[m][n][r] + dwv;
                    float e = __expf(2.0f * fabsf(x));
                    float th = copysignf(1.0f - __fdividef(2.0f, e + 1.0f), x);
                    sc[m][r] += th * wo;
                }
            }
    }
    // reduce across the 16 col-lanes, then across the 4 wave-cols via LDS atomics
#pragma unroll
    for (int m = 0; m < 4; ++m) {
#pragma unroll
        for (int r = 0; r < 4; ++r) {
            float v = sc[m][r];
            v += __shfl_xor(v, 1);
            v += __shfl_xor(v, 2);
            v += __shfl_xor(v, 4);
            v += __shfl_xor(v, 8);
            sc[m][r] = v;
        }
        if ((lane & 15) == 0) {
            int rb = wr * 64 + m * 16 + (lane >> 4) * 4;
#pragma unroll
            for (int r = 0; r < 4; ++r)
                atomicAdd(&score_lds[rb + r], sc[m][r]);
        }
    }
    __syncthreads();
    if (tid < 128) scores[m0 + tid] = score_lds[tid];
#undef LOAD_A
#undef LOAD_B
}

// ---------------- kernel 3: masked softmax over N per batch ----------------
// NOTE: mask is a bool input -> harness pushes integer inputs as int32.
__global__ void k_softmax(const float* __restrict__ scores,
                          const int* __restrict__ mask,
                          float* __restrict__ probs, float* __restrict__ out_probs) {
    int b = blockIdx.x, tid = threadIdx.x;
    __shared__ float red[8];
    float v[8];
    float m = -INFINITY;
#pragma unroll
    for (int i = 0; i < 8; ++i) {
        int n = tid + i * 256;
        float s = scores[b * 2048 + n];
        s = (mask[b * 2048 + n] != 0) ? s : -INFINITY;
        v[i] = s;
        m = fmaxf(m, s);
    }
    for (int off = 32; off; off >>= 1) m = fmaxf(m, __shfl_xor(m, off));
    if ((tid & 63) == 0) red[tid >> 6] = m;
    __syncthreads();
    m = fmaxf(fmaxf(red[0], red[1]), fmaxf(red[2], red[3]));
    float sum = 0.f;
#pragma unroll
    for (int i = 0; i < 8; ++i) {
        v[i] = expf(v[i] - m);
        sum += v[i];
    }
    for (int off = 32; off; off >>= 1) sum += __shfl_xor(sum, off);
    if ((tid & 63) == 0) red[4 + (tid >> 6)] = sum;
    __syncthreads();
    sum = red[4] + red[5] + red[6] + red[7];
    float inv = 1.0f / sum;
#pragma unroll
    for (int i = 0; i < 8; ++i) {
        int n = tid + i * 256;
        float p = v[i] * inv;
        probs[b * 2048 + n]     = p;
        out_probs[b * 2048 + n] = p;
    }
}

// ---------------- kernel 4: attn[b,e] = sum_n probs[b,n]*enc[b,n,e] ----------
// grid (32 batches x 4 e-chunks) x 256 threads: 128 blocks instead of 32.
__global__ void k_attn(const float* __restrict__ probs, const float* __restrict__ enc,
                       float* __restrict__ attn) {
    __shared__ float pl[2048];
    int b = blockIdx.x, q = blockIdx.y, t = threadIdx.x;
    for (int i = t; i < 2048; i += 256) pl[i] = probs[b * 2048 + i];
    __syncthreads();
    const float* er = enc + (size_t)b * 2048 * 1024 + q * 256 + t;
    float acc = 0.f;
    for (int n = 0; n < 2048; ++n) {
        float p = pl[n];
        if (p >= 1e-12f)   // uniform branch; dropped mass error <= 2e-9
            acc += p * er[(size_t)n * 1024];
    }
    attn[b * 1024 + q * 256 + t] = acc;
}

extern "C" void kernel_launch(void* const* d_in, const int* in_sizes, int n_in,
                              void* d_out, int out_size, void* d_ws, size_t ws_size,
                              hipStream_t stream) {
    const float* enc          = (const float*)d_in[0];  // [32,2048,1024]
    const float* dec          = (const float*)d_in[1];  // [32,1024]
    const int*   mask         = (const int*)d_in[2];    // [32,2048] bool -> int32
    const float* w_e          = (const float*)d_in[3];  // [1024,1024]
    const float* w_d          = (const float*)d_in[4];  // [1024,1024]
    const float* w_out        = (const float*)d_in[5];  // [1024]

    float* out_attn  = (float*)d_out;              // [32*1024]
    float* out_probs = out_attn + Bsz * Hdim;      // [32*2048]

    // workspace layout (~4.7 MB)
    float* dw        = (float*)d_ws;               // 32*1024
    float* scores    = dw + Bsz * Hdim;            // 32*2048
    float* probs     = scores + Bsz * Nseq;        // 32*2048
    _Float16* w_hiT  = (_Float16*)(probs + Bsz * Nseq);  // [1024*1024]
    _Float16* w_loT  = w_hiT + Edim * Hdim;

    k_dw<<<dim3(32, 4), dim3(256), 0, stream>>>(dec, w_d, dw);
    k_split<<<dim3(32, 32), dim3(256), 0, stream>>>(w_e, w_hiT, w_loT);
    k_scores<<<dim3(512), dim3(512), 0, stream>>>(enc, w_hiT, w_loT, dw, w_out, scores);
    k_softmax<<<dim3(32), dim3(256), 0, stream>>>(scores, mask, probs, out_probs);
    k_attn<<<dim3(32, 4), dim3(256), 0, stream>>>(probs, enc, out_attn);
}

// Round 4
// 565.733 us; speedup vs baseline: 1.8599x; 1.6092x over previous
//
#include <hip/hip_runtime.h>
#include <hip/hip_bf16.h>

typedef _Float16 half8 __attribute__((ext_vector_type(8)));
typedef float f32x4 __attribute__((ext_vector_type(4)));

#define Bsz 32
#define Nseq 2048
#define Edim 1024
#define Hdim 1024

// async global->LDS, 16B per lane. LDS dest = wave-uniform base + lane*16.
__device__ __forceinline__ void gload_lds16(const void* g, void* l) {
    __builtin_amdgcn_global_load_lds(
        (const __attribute__((address_space(1))) unsigned int*)g,
        (__attribute__((address_space(3))) unsigned int*)l, 16, 0, 0);
}

// ---------------- kernel 1a: dw[b,h] = dec[b,:] @ w_d[:,h]  (f32) ------------
__global__ void k_dw(const float* __restrict__ dec, const float* __restrict__ w_d,
                     float* __restrict__ dw) {
    int b = blockIdx.x;
    int h = blockIdx.y * 256 + threadIdx.x;
    const float* dr = dec + b * 1024;
    float a0 = 0.f, a1 = 0.f, a2 = 0.f, a3 = 0.f;   // 4 chains: hide L2 latency
    for (int d = 0; d < 1024; d += 4) {
        a0 += dr[d + 0] * w_d[(d + 0) * 1024 + h];
        a1 += dr[d + 1] * w_d[(d + 1) * 1024 + h];
        a2 += dr[d + 2] * w_d[(d + 2) * 1024 + h];
        a3 += dr[d + 3] * w_d[(d + 3) * 1024 + h];
    }
    dw[b * 1024 + h] = (a0 + a1) + (a2 + a3);
}

// ------- kernel 1b: split w_e (f32 [E][H]) into fp16 hi/lo, transposed [H][E] -
__global__ void k_split(const float* __restrict__ w_e,
                        _Float16* __restrict__ w_hiT, _Float16* __restrict__ w_loT) {
    __shared__ _Float16 th[32][33];
    __shared__ _Float16 tl[32][33];
    int e0 = blockIdx.x * 32, h0 = blockIdx.y * 32;
    int tx = threadIdx.x & 31, ty = threadIdx.x >> 5;  // ty 0..7
#pragma unroll
    for (int i = 0; i < 4; ++i) {
        int r = ty + i * 8;
        float x = w_e[(size_t)(e0 + r) * 1024 + h0 + tx];
        _Float16 h = (_Float16)x;
        th[r][tx] = h;
        tl[r][tx] = (_Float16)(x - (float)h);
    }
    __syncthreads();
#pragma unroll
    for (int i = 0; i < 4; ++i) {
        int r = ty + i * 8;
        w_hiT[(size_t)(h0 + r) * 1024 + e0 + tx] = th[tx][r];
        w_loT[(size_t)(h0 + r) * 1024 + e0 + tx] = tl[tx][r];
    }
}

// ---------------- kernel 2: scores[m] = sum_h w_out[h]*tanh((enc@w_e)[m,h]+dw[b,h])
// fp16x3 split MFMA, 16x16x32. 512 thr (8 waves, 2x4), M_TILE=128, H_CHUNK=256,
// K_STEP=32, flat tile loop t=0..127 (hc = t>>5, kt = t&31).
//
// 2-phase dbuf pipeline (T3 minimum recipe):
//   per tile: issue B global_load_lds(t+1 -> buf^1) | convert+ds_write A(t+1)
//             | issue A raw loads(t+2) | ds_read frags(buf) | 48 MFMA
//             | one __syncthreads (vmcnt0+lgkmcnt0 drain).
// Dynamic LDS 98816B (A 2x(8+8)KB, B 2x(16+16)KB, scores 512B) -> 1 block/CU.
__global__ __launch_bounds__(512, 2)
void k_scores(const float* __restrict__ enc,
              const _Float16* __restrict__ w_hiT, const _Float16* __restrict__ w_loT,
              const float* __restrict__ dw, const float* __restrict__ w_out,
              float* __restrict__ scores) {
    extern __shared__ __align__(16) char smem[];
    // byte layout:
    //   A hi buf0/1 : 0 / 8192        ([4 ks][128 row][16B])
    //   A lo buf0/1 : 16384 / 24576
    //   B hi buf0/1 : 32768 / 49152   ([4 ks][256 row][16B])
    //   B lo buf0/1 : 65536 / 81920
    //   scoreL      : 98304 (128 f32)
    float* scoreL = (float*)(smem + 98304);

    const int tid  = threadIdx.x;
    const int lane = tid & 63;
    const int wave = tid >> 6;
    const int wr = wave >> 2, wc = wave & 3;
    const int m0 = blockIdx.x * 128;
    const int bb = m0 >> 11;
    const float* dwb = dw + bb * 1024;

    // A staging: thread stages 8 f32 of row a_row at kseg a_ks
    const int a_row = tid >> 2, a_ks = tid & 3;
    const float* aBase = enc + (size_t)(m0 + a_row) * 1024 + a_ks * 8;
    // B staging via global_load_lds: lds byte = tid*16 = (tid>>8)*4096 + (tid&255)*16
    const int b_row = tid & 255, b_ks = tid >> 8;   // ks 0/1 (instr2 adds 2)
    const _Float16* bhBase = w_hiT + (size_t)b_row * 1024 + b_ks * 8;
    const _Float16* blBase = w_loT + (size_t)b_row * 1024 + b_ks * 8;
    const int wofs = wave * 1024;    // per-wave uniform LDS chunk

    float sc[4][4];
#pragma unroll
    for (int m = 0; m < 4; ++m)
#pragma unroll
        for (int r = 0; r < 4; ++r) sc[m][r] = 0.f;
    if (tid < 128) scoreL[tid] = 0.f;

    f32x4 acc[4][4];
#pragma unroll
    for (int m = 0; m < 4; ++m)
#pragma unroll
        for (int n = 0; n < 4; ++n) acc[m][n] = (f32x4){0.f, 0.f, 0.f, 0.f};

    float4 pa0, pa1;   // raw A prefetch regs

#define A_LOAD(t) do { \
        const float* _p = aBase + (((t) & 31) << 5); \
        pa0 = ((const float4*)_p)[0]; \
        pa1 = ((const float4*)_p)[1]; \
    } while (0)
#define B_ISSUE(t, buf) do { \
        const size_t _g = ((size_t)((t) >> 5) << 18) + (size_t)(((t) & 31) << 5); \
        char* _bh = smem + 32768 + (buf) * 16384; \
        char* _bl = smem + 65536 + (buf) * 16384; \
        gload_lds16(bhBase + _g,      _bh + wofs); \
        gload_lds16(bhBase + _g + 16, _bh + 8192 + wofs); \
        gload_lds16(blBase + _g,      _bl + wofs); \
        gload_lds16(blBase + _g + 16, _bl + 8192 + wofs); \
    } while (0)
#define A_STAGE(buf) do { \
        float _q[8] = {pa0.x, pa0.y, pa0.z, pa0.w, pa1.x, pa1.y, pa1.z, pa1.w}; \
        half8 _hi, _lo; \
        _Pragma("unroll") \
        for (int _j = 0; _j < 8; ++_j) { \
            _Float16 _h = (_Float16)_q[_j]; \
            _hi[_j] = _h; \
            _lo[_j] = (_Float16)(_q[_j] - (float)_h); \
        } \
        *(half8*)(smem + (buf) * 8192 + a_ks * 2048 + a_row * 16) = _hi; \
        *(half8*)(smem + 16384 + (buf) * 8192 + a_ks * 2048 + a_row * 16) = _lo; \
    } while (0)

    // prologue: stage tile 0 into buf0, prefetch A(1)
    A_LOAD(0);
    B_ISSUE(0, 0);
    A_STAGE(0);
    A_LOAD(1);
    __syncthreads();

    const int ks = lane >> 4, rb = lane & 15;

    for (int t = 0; t < 128; ++t) {
        const int cur = t & 1;
        if (t < 127) {
            B_ISSUE(t + 1, cur ^ 1);   // async, lands under the MFMAs below
            A_STAGE(cur ^ 1);          // convert A(t+1) from pa, write LDS
            if (t < 126) A_LOAD(t + 2);
        }
        // ---- fragments from buf cur ----
        const char* sah = smem + cur * 8192;
        const char* sal = smem + 16384 + cur * 8192;
        const char* sbh = smem + 32768 + cur * 16384;
        const char* sbl = smem + 65536 + cur * 16384;
        half8 ah[4], al[4], bh[4], bl[4];
#pragma unroll
        for (int m = 0; m < 4; ++m) {
            int off = ks * 2048 + (wr * 64 + m * 16 + rb) * 16;
            ah[m] = *(const half8*)(sah + off);
            al[m] = *(const half8*)(sal + off);
        }
#pragma unroll
        for (int n = 0; n < 4; ++n) {
            int off = ks * 4096 + (wc * 64 + n * 16 + rb) * 16;
            bh[n] = *(const half8*)(sbh + off);
            bl[n] = *(const half8*)(sbl + off);
        }
        __builtin_amdgcn_s_setprio(1);
#pragma unroll
        for (int m = 0; m < 4; ++m)
#pragma unroll
            for (int n = 0; n < 4; ++n) {
                acc[m][n] = __builtin_amdgcn_mfma_f32_16x16x32_f16(ah[m], bh[n], acc[m][n], 0, 0, 0);
                acc[m][n] = __builtin_amdgcn_mfma_f32_16x16x32_f16(ah[m], bl[n], acc[m][n], 0, 0, 0);
                acc[m][n] = __builtin_amdgcn_mfma_f32_16x16x32_f16(al[m], bh[n], acc[m][n], 0, 0, 0);
            }
        __builtin_amdgcn_s_setprio(0);

        if ((t & 31) == 31) {
            // ---- epilogue for hc = t>>5: tanh + w_out, then reset acc ----
            const int h0 = (t >> 5) << 8;
#pragma unroll
            for (int m = 0; m < 4; ++m)
#pragma unroll
                for (int n = 0; n < 4; ++n) {
                    int h = h0 + wc * 64 + n * 16 + rb;
                    float dwv = dwb[h];
                    float wo  = w_out[h];
#pragma unroll
                    for (int r = 0; r < 4; ++r) {
                        float x = acc[m][n][r] + dwv;
                        float e = __expf(2.0f * fabsf(x));
                        float th = copysignf(1.0f - __fdividef(2.0f, e + 1.0f), x);
                        sc[m][r] += th * wo;
                    }
                    acc[m][n] = (f32x4){0.f, 0.f, 0.f, 0.f};
                }
        }
        __syncthreads();   // drain vm+lgkm: tile t+1 fully staged; cur free
    }

    // reduce across the 16 col-lanes, then across the 4 wave-cols via LDS atomics
#pragma unroll
    for (int m = 0; m < 4; ++m) {
#pragma unroll
        for (int r = 0; r < 4; ++r) {
            float v = sc[m][r];
            v += __shfl_xor(v, 1);
            v += __shfl_xor(v, 2);
            v += __shfl_xor(v, 4);
            v += __shfl_xor(v, 8);
            sc[m][r] = v;
        }
        if ((lane & 15) == 0) {
            int rbase = wr * 64 + m * 16 + (lane >> 4) * 4;
#pragma unroll
            for (int r = 0; r < 4; ++r)
                atomicAdd(&scoreL[rbase + r], sc[m][r]);
        }
    }
    __syncthreads();
    if (tid < 128) scores[m0 + tid] = scoreL[tid];
#undef A_LOAD
#undef B_ISSUE
#undef A_STAGE
}

// ---------------- kernel 3: masked softmax over N per batch ----------------
// mask is bool in python -> pushed as int32.
__global__ void k_softmax(const float* __restrict__ scores,
                          const int* __restrict__ mask,
                          float* __restrict__ probs, float* __restrict__ out_probs) {
    int b = blockIdx.x, tid = threadIdx.x;
    __shared__ float red[8];
    float v[8];
    float m = -INFINITY;
#pragma unroll
    for (int i = 0; i < 8; ++i) {
        int n = tid + i * 256;
        float s = scores[b * 2048 + n];
        s = (mask[b * 2048 + n] != 0) ? s : -INFINITY;
        v[i] = s;
        m = fmaxf(m, s);
    }
    for (int off = 32; off; off >>= 1) m = fmaxf(m, __shfl_xor(m, off));
    if ((tid & 63) == 0) red[tid >> 6] = m;
    __syncthreads();
    m = fmaxf(fmaxf(red[0], red[1]), fmaxf(red[2], red[3]));
    float sum = 0.f;
#pragma unroll
    for (int i = 0; i < 8; ++i) {
        v[i] = expf(v[i] - m);
        sum += v[i];
    }
    for (int off = 32; off; off >>= 1) sum += __shfl_xor(sum, off);
    if ((tid & 63) == 0) red[4 + (tid >> 6)] = sum;
    __syncthreads();
    sum = red[4] + red[5] + red[6] + red[7];
    float inv = 1.0f / sum;
#pragma unroll
    for (int i = 0; i < 8; ++i) {
        int n = tid + i * 256;
        float p = v[i] * inv;
        probs[b * 2048 + n]     = p;
        out_probs[b * 2048 + n] = p;
    }
}

// ---------------- kernel 4: attn[b,e] += sum_n probs[b,n]*enc[b,n,e] --------
// grid (32, 16); block (b,c) owns rows c*128..+127. Survivor compaction first
// (softmax is near-one-hot; ~90%+ of rows have p<1e-12), then an unconditional
// load/FMA loop the compiler can pipeline. Partial sums atomicAdd into attn
// (memset to 0 beforehand).
__global__ void k_attn(const float* __restrict__ probs, const float* __restrict__ enc,
                       float* __restrict__ attn) {
    __shared__ float pv[128];
    __shared__ int   pidx[128];
    __shared__ int   cnt;
    int b = blockIdx.x, c = blockIdx.y, t = threadIdx.x;
    if (t == 0) cnt = 0;
    __syncthreads();
    if (t < 128) {
        float p = probs[b * 2048 + c * 128 + t];
        if (p >= 1e-12f) {   // dropped mass <= 2048e-12 -> attn err <= ~1e-8
            int slot = atomicAdd(&cnt, 1);
            pv[slot]   = p;
            pidx[slot] = c * 128 + t;
        }
    }
    __syncthreads();
    int nk = cnt;
    if (nk == 0) return;
    const float* eb = enc + (size_t)b * 2048 * 1024;
    float4 acc = {0.f, 0.f, 0.f, 0.f};
    for (int i = 0; i < nk; ++i) {
        float p = pv[i];
        float4 v = ((const float4*)(eb + (size_t)pidx[i] * 1024))[t];
        acc.x += p * v.x;
        acc.y += p * v.y;
        acc.z += p * v.z;
        acc.w += p * v.w;
    }
    float* o = attn + b * 1024 + t * 4;
    atomicAdd(o + 0, acc.x);
    atomicAdd(o + 1, acc.y);
    atomicAdd(o + 2, acc.z);
    atomicAdd(o + 3, acc.w);
}

extern "C" void kernel_launch(void* const* d_in, const int* in_sizes, int n_in,
                              void* d_out, int out_size, void* d_ws, size_t ws_size,
                              hipStream_t stream) {
    const float* enc   = (const float*)d_in[0];  // [32,2048,1024]
    const float* dec   = (const float*)d_in[1];  // [32,1024]
    const int*   mask  = (const int*)d_in[2];    // [32,2048] bool -> int32
    const float* w_e   = (const float*)d_in[3];  // [1024,1024]
    const float* w_d   = (const float*)d_in[4];  // [1024,1024]
    const float* w_out = (const float*)d_in[5];  // [1024]

    float* out_attn  = (float*)d_out;              // [32*1024]
    float* out_probs = out_attn + Bsz * Hdim;      // [32*2048]

    // workspace layout (~4.7 MB)
    float* dw        = (float*)d_ws;               // 32*1024
    float* scores    = dw + Bsz * Hdim;            // 32*2048
    float* probs     = scores + Bsz * Nseq;        // 32*2048
    _Float16* w_hiT  = (_Float16*)(probs + Bsz * Nseq);  // [1024*1024]
    _Float16* w_loT  = w_hiT + Edim * Hdim;

    static const int kScoresLds = 98816;
    hipFuncSetAttribute((const void*)k_scores,
                        hipFuncAttributeMaxDynamicSharedMemorySize, kScoresLds);

    hipMemsetAsync(out_attn, 0, Bsz * Hdim * sizeof(float), stream);
    k_dw<<<dim3(32, 4), dim3(256), 0, stream>>>(dec, w_d, dw);
    k_split<<<dim3(32, 32), dim3(256), 0, stream>>>(w_e, w_hiT, w_loT);
    k_scores<<<dim3(512), dim3(512), kScoresLds, stream>>>(enc, w_hiT, w_loT, dw, w_out, scores);
    k_softmax<<<dim3(32), dim3(256), 0, stream>>>(scores, mask, probs, out_probs);
    k_attn<<<dim3(32, 16), dim3(256), 0, stream>>>(probs, enc, out_attn);
}